// Round 3
// baseline (703.250 us; speedup 1.0000x reference)
//
#include <hip/hip_runtime.h>
#include <hip/hip_bf16.h>
#include <math.h>

// Model constants (fixed by the reference)
#define D_MODEL 768
#define N_LAYER 4
#define D_STATE 16
#define D_CONV  4
#define DT_RANK 48
#define D_INNER 1536
#define B_SZ    2
#define L_SEQ   1024
#define N_MELS  80
#define ROWS    (B_SZ * L_SEQ)   // 2048

typedef __bf16 bf16x8 __attribute__((ext_vector_type(8)));
typedef float  f32x4  __attribute__((ext_vector_type(4)));

// raw transcendentals (1 ulp; v_exp_f32 computes 2^x)
__device__ __forceinline__ float fast_exp2(float x) {
    float r; asm("v_exp_f32 %0, %1" : "=v"(r) : "v"(x)); return r;
}
__device__ __forceinline__ float fast_exp(float x) {
    return fast_exp2(x * 1.44269504f);
}
__device__ __forceinline__ float fast_rcp(float x) {
    float r; asm("v_rcp_f32 %0, %1" : "=v"(r) : "v"(x)); return r;
}
__device__ __forceinline__ float silu_f(float v) {
    return v * fast_rcp(1.0f + fast_exp(-v));
}
__device__ __forceinline__ float softplus_f(float v) {
    return fmaxf(v, 0.0f) + log1pf(expf(-fabsf(v)));
}
__device__ __forceinline__ unsigned short f2bf(float f) {
    unsigned int u = __float_as_uint(f);
    unsigned int r = (u + 0x7FFFu + ((u >> 16) & 1u)) >> 16;
    return (unsigned short)r;
}
__device__ __forceinline__ float bf2f(unsigned short v) {
    return __uint_as_float(((unsigned int)v) << 16);
}

// async 16B global -> LDS: dest = wave-uniform LDS base + lane*16
typedef __attribute__((address_space(1))) const unsigned int gconst_u32;
typedef __attribute__((address_space(3))) unsigned int lds_u32;
__device__ __forceinline__ void gload16(void* lds, const void* g) {
    __builtin_amdgcn_global_load_lds((gconst_u32*)g, (lds_u32*)lds, 16, 0, 0);
}

// ---------------- embedding gather ----------------
__global__ void embed_kernel(const int* __restrict__ ids,
                             const float* __restrict__ emb,
                             float* __restrict__ x) {
    int i = blockIdx.x * 256 + threadIdx.x;
    if (i >= ROWS * D_MODEL) return;
    int r = i / D_MODEL, c = i - r * D_MODEL;
    x[i] = emb[(size_t)ids[r] * D_MODEL + c];
}

// ---------------- rmsnorm -> bf16 ----------------
__global__ void rmsnorm_kernel(const float* __restrict__ x,
                               const float* __restrict__ w,
                               unsigned short* __restrict__ hb) {
    int row = blockIdx.x;
    const float* xr = x + (size_t)row * D_MODEL;
    int tid = threadIdx.x;
    float p = 0.f;
    for (int c = tid; c < D_MODEL; c += 256) { float v = xr[c]; p = fmaf(v, v, p); }
    for (int off = 32; off >= 1; off >>= 1) p += __shfl_down(p, off, 64);
    __shared__ float ws[4];
    int lane = tid & 63, wv = tid >> 6;
    if (lane == 0) ws[wv] = p;
    __syncthreads();
    if (tid == 0) ws[0] = ws[0] + ws[1] + ws[2] + ws[3];
    __syncthreads();
    float scale = 1.0f / sqrtf(ws[0] / (float)D_MODEL + 1e-5f);
    for (int c = tid; c < D_MODEL; c += 256)
        hb[(size_t)row * D_MODEL + c] = f2bf(xr[c] * scale * w[c]);
}

// ---------------- per-layer fused weight prep (1 dispatch) ---------------
__global__ void prep_weights_kernel(const float* __restrict__ in_wi,
                                    const float* __restrict__ out_wi,
                                    const float* __restrict__ xp_wi,
                                    const float* __restrict__ dt_wi,
                                    unsigned short* __restrict__ wt_in,
                                    unsigned short* __restrict__ wt_out,
                                    unsigned short* __restrict__ xpT,
                                    unsigned short* __restrict__ dtwT) {
    __shared__ float t[32][33];
    int bx = blockIdx.x;
    int tid = threadIdx.x;
    if (bx < 3456) {
        const float* src; unsigned short* dst; int R, C, cy, cx;
        if (bx < 2304) {
            src = in_wi; dst = wt_in; R = D_MODEL; C = 2 * D_INNER;
            cy = bx / 96; cx = bx - cy * 96;
        } else {
            int tt = bx - 2304;
            src = out_wi; dst = wt_out; R = D_INNER; C = D_MODEL;
            cy = tt / 24; cx = tt - cy * 24;
        }
        int tx = tid & 31, ty = tid >> 5;
        int r0 = cy * 32, c0 = cx * 32;
#pragma unroll
        for (int i = 0; i < 4; i++)
            t[ty + i * 8][tx] = src[(size_t)(r0 + ty + i * 8) * C + c0 + tx];
        __syncthreads();
#pragma unroll
        for (int i = 0; i < 4; i++)
            dst[(size_t)(c0 + ty + i * 8) * R + r0 + tx] = f2bf(t[tx][ty + i * 8]);
    } else {
        int i = (bx - 3456) * 256 + tid;
        if (i < 80 * D_INNER) {
            int c = i / D_INNER, r = i - c * D_INNER;
            xpT[i] = f2bf(xp_wi[(size_t)r * 80 + c]);
        } else {
            int i2 = i - 80 * D_INNER;   // < 1536*64
            int c = i2 >> 6, r = i2 & 63;
            dtwT[i2] = (r < DT_RANK) ? f2bf(dt_wi[(size_t)r * D_INNER + c])
                                     : (unsigned short)0;
        }
    }
}

// ---------------- bf16 [R][C] -> bf16 [C][R] (32x32 tiles) ---------------
__global__ void transpose_u16_kernel(const unsigned short* __restrict__ src,
                                     unsigned short* __restrict__ dst,
                                     int R, int C) {
    __shared__ unsigned short t[32][34];
    int tx = threadIdx.x & 31, ty = threadIdx.x >> 5;
    int r0 = blockIdx.y * 32, c0 = blockIdx.x * 32;
#pragma unroll
    for (int i = 0; i < 4; i++)
        t[ty + i * 8][tx] = src[(size_t)(r0 + ty + i * 8) * C + c0 + tx];
    __syncthreads();
#pragma unroll
    for (int i = 0; i < 4; i++)
        dst[(size_t)(c0 + ty + i * 8) * R + r0 + tx] = t[tx][ty + i * 8];
}

// ---------------- fp32 [R][C] -> bf16 [C][Rpad], zero-fill r>=R ----------
__global__ void transpose_pad_bf16_kernel(const float* __restrict__ src,
                                          unsigned short* __restrict__ dst,
                                          int R, int C, int Rpad) {
    int i = blockIdx.x * 256 + threadIdx.x;
    if (i >= C * Rpad) return;
    int c = i / Rpad, r = i - c * Rpad;
    dst[i] = (r < R) ? f2bf(src[(size_t)r * C + c]) : (unsigned short)0;
}

// ---------------- split-K reduce (+ fused bf16 [ROWS][64] cvt) -----------
__global__ void reduce_cvt_kernel(const float* __restrict__ part,
                                  float* __restrict__ xdbl,
                                  unsigned short* __restrict__ xdblb,
                                  int nsplit) {
    int i = blockIdx.x * 256 + threadIdx.x;
    if (i >= ROWS * 80) return;
    float s = 0.f;
    for (int k = 0; k < nsplit; k++) s += part[(size_t)k * ROWS * 80 + i];
    xdbl[i] = s;
    int r = i / 80, c = i - r * 80;
    if (c < DT_RANK) xdblb[r * 64 + c] = f2bf(s);
    else if (c >= 64) xdblb[r * 64 + c - 16] = 0;
}

// ---------------- plain split-K reduce (head) ----------------------------
__global__ void reduce_split_kernel(const float* __restrict__ part,
                                    float* __restrict__ dst,
                                    int MN, int nsplit) {
    int i = blockIdx.x * 256 + threadIdx.x;
    if (i >= MN) return;
    float s = 0.f;
    for (int k = 0; k < nsplit; k++) s += part[(size_t)k * MN + i];
    dst[i] = s;
}

// ---------------- bf16 MFMA GEMM, 64x128, BK=64, global_load_lds dbuf ----
// grid (N/128, M/64). R12: same tile/grid as the 682us version (3 blk/CU at
// in_proj), staging swapped reg->async DMA (Common-mistake #1; m193 +67%,
// m151 glds>reg at this occupancy). Linear LDS [rows][64] (gload_lds needs
// contiguous lane-order dest); ~4-way ds_read conflicts accepted (hidden at
// 2-phase, m233/m252). LDS 48KB -> 3 blocks/CU.
__global__ __launch_bounds__(256) void mfma_gemm64(
        const unsigned short* __restrict__ A,
        const unsigned short* __restrict__ BT,
        const float* __restrict__ bias, const float* __restrict__ resid,
        float* __restrict__ Cf, unsigned short* __restrict__ Cb,
        int M, int N, int K, int ldc, int act, int bias_mode) {
    __shared__ __align__(16) unsigned short As[2][64 * 64];
    __shared__ __align__(16) unsigned short Bs[2][128 * 64];
    int tid = threadIdx.x;
    int row0 = blockIdx.y * 64, col0 = blockIdx.x * 128;
    int wave = tid >> 6, lane = tid & 63;
    int wr = (wave >> 1) * 32, wc = (wave & 1) * 64;
    int lm = lane & 15, lq = lane >> 4;
    int srow = tid >> 3, seg = tid & 7;      // 32 rows/call, 8x16B segs/row
    const unsigned short* ApA = A  + (size_t)(row0 + srow) * K + seg * 8;
    const unsigned short* ApB = A  + (size_t)(row0 + 32 + srow) * K + seg * 8;
    const unsigned short* Bp0 = BT + (size_t)(col0 + srow) * K + seg * 8;
    const unsigned short* Bp1 = BT + (size_t)(col0 + 32 + srow) * K + seg * 8;
    const unsigned short* Bp2 = BT + (size_t)(col0 + 64 + srow) * K + seg * 8;
    const unsigned short* Bp3 = BT + (size_t)(col0 + 96 + srow) * K + seg * 8;
    int wb = wave * 512;                     // wave covers 8 rows x 64 elems
    f32x4 acc[2][4] = {};
    // prologue: stage k-tile 0 into buf 0
    gload16(&As[0][wb], ApA);
    gload16(&As[0][2048 + wb], ApB);
    gload16(&Bs[0][wb], Bp0);
    gload16(&Bs[0][2048 + wb], Bp1);
    gload16(&Bs[0][4096 + wb], Bp2);
    gload16(&Bs[0][6144 + wb], Bp3);
    __syncthreads();
    int nk = K >> 6, cur = 0;
    for (int t = 0; t < nk; ++t) {
        int cn = cur ^ 1;
        if (t + 1 < nk) {
            int ko = (t + 1) << 6;
            gload16(&As[cn][wb], ApA + ko);
            gload16(&As[cn][2048 + wb], ApB + ko);
            gload16(&Bs[cn][wb], Bp0 + ko);
            gload16(&Bs[cn][2048 + wb], Bp1 + ko);
            gload16(&Bs[cn][4096 + wb], Bp2 + ko);
            gload16(&Bs[cn][6144 + wb], Bp3 + ko);
        }
#pragma unroll
        for (int ks = 0; ks < 2; ks++) {
            bf16x8 af[2], bfr[4];
#pragma unroll
            for (int i = 0; i < 2; i++)
                af[i] = *(const bf16x8*)&As[cur][(wr + i * 16 + lm) * 64 + ks * 32 + lq * 8];
#pragma unroll
            for (int j = 0; j < 4; j++)
                bfr[j] = *(const bf16x8*)&Bs[cur][(wc + j * 16 + lm) * 64 + ks * 32 + lq * 8];
#pragma unroll
            for (int i = 0; i < 2; i++)
#pragma unroll
                for (int j = 0; j < 4; j++)
                    acc[i][j] = __builtin_amdgcn_mfma_f32_16x16x32_bf16(af[i], bfr[j], acc[i][j], 0, 0, 0);
        }
        __syncthreads();                     // drains vmcnt -> buf cn ready
        cur = cn;
    }
#pragma unroll
    for (int i = 0; i < 2; i++) {
#pragma unroll
        for (int ii = 0; ii < 4; ii++) {
            int row = row0 + wr + i * 16 + lq * 4 + ii;
#pragma unroll
            for (int j = 0; j < 4; j++) {
                int col = col0 + wc + j * 16 + lm;
                float v = acc[i][j][ii];
                if (bias) v += bias[bias_mode ? row : col];
                if (act == 1) v = softplus_f(v);
                if (resid) v += resid[(size_t)row * ldc + col];
                if (Cf) Cf[(size_t)row * ldc + col] = v;
                else    Cb[(size_t)row * ldc + col] = f2bf(v);
            }
        }
    }
}

// ---------------- bf16 MFMA GEMM, 32x128, BK=64, global_load_lds dbuf ----
// grid (N/128, M/32). 4 waves side by side (32 cols each). acc 2x2/wave.
// LDS 40KB -> 4 blocks/CU.
__global__ __launch_bounds__(256) void mfma_gemm32(
        const unsigned short* __restrict__ A,
        const unsigned short* __restrict__ BT,
        const float* __restrict__ bias, const float* __restrict__ resid,
        float* __restrict__ Cf, unsigned short* __restrict__ Cb,
        int M, int N, int K, int ldc, int act, int bias_mode) {
    __shared__ __align__(16) unsigned short As[2][32 * 64];
    __shared__ __align__(16) unsigned short Bs[2][128 * 64];
    int tid = threadIdx.x;
    int row0 = blockIdx.y * 32, col0 = blockIdx.x * 128;
    int wave = tid >> 6, lane = tid & 63;
    int wc = wave * 32;
    int lm = lane & 15, lq = lane >> 4;
    int srow = tid >> 3, seg = tid & 7;
    const unsigned short* ApA = A  + (size_t)(row0 + srow) * K + seg * 8;
    const unsigned short* Bp0 = BT + (size_t)(col0 + srow) * K + seg * 8;
    const unsigned short* Bp1 = BT + (size_t)(col0 + 32 + srow) * K + seg * 8;
    const unsigned short* Bp2 = BT + (size_t)(col0 + 64 + srow) * K + seg * 8;
    const unsigned short* Bp3 = BT + (size_t)(col0 + 96 + srow) * K + seg * 8;
    int wb = wave * 512;
    f32x4 acc[2][2] = {};
    gload16(&As[0][wb], ApA);
    gload16(&Bs[0][wb], Bp0);
    gload16(&Bs[0][2048 + wb], Bp1);
    gload16(&Bs[0][4096 + wb], Bp2);
    gload16(&Bs[0][6144 + wb], Bp3);
    __syncthreads();
    int nk = K >> 6, cur = 0;
    for (int t = 0; t < nk; ++t) {
        int cn = cur ^ 1;
        if (t + 1 < nk) {
            int ko = (t + 1) << 6;
            gload16(&As[cn][wb], ApA + ko);
            gload16(&Bs[cn][wb], Bp0 + ko);
            gload16(&Bs[cn][2048 + wb], Bp1 + ko);
            gload16(&Bs[cn][4096 + wb], Bp2 + ko);
            gload16(&Bs[cn][6144 + wb], Bp3 + ko);
        }
#pragma unroll
        for (int ks = 0; ks < 2; ks++) {
            bf16x8 af[2], bfr[2];
#pragma unroll
            for (int i = 0; i < 2; i++)
                af[i] = *(const bf16x8*)&As[cur][(i * 16 + lm) * 64 + ks * 32 + lq * 8];
#pragma unroll
            for (int j = 0; j < 2; j++)
                bfr[j] = *(const bf16x8*)&Bs[cur][(wc + j * 16 + lm) * 64 + ks * 32 + lq * 8];
#pragma unroll
            for (int i = 0; i < 2; i++)
#pragma unroll
                for (int j = 0; j < 2; j++)
                    acc[i][j] = __builtin_amdgcn_mfma_f32_16x16x32_bf16(af[i], bfr[j], acc[i][j], 0, 0, 0);
        }
        __syncthreads();
        cur = cn;
    }
#pragma unroll
    for (int i = 0; i < 2; i++) {
#pragma unroll
        for (int ii = 0; ii < 4; ii++) {
            int row = row0 + i * 16 + lq * 4 + ii;
#pragma unroll
            for (int j = 0; j < 2; j++) {
                int col = col0 + wc + j * 16 + lm;
                float v = acc[i][j][ii];
                if (bias) v += bias[bias_mode ? row : col];
                if (act == 1) v = softplus_f(v);
                if (resid) v += resid[(size_t)row * ldc + col];
                if (Cf) Cf[(size_t)row * ldc + col] = v;
                else    Cb[(size_t)row * ldc + col] = f2bf(v);
            }
        }
    }
}

// ---------------- skinny split-K bf16 MFMA -> private partials -----------
// N fixed at 80 (NT=5 compile-time; R6 spill lesson). Reg-pipelined.
// (80-row B tile doesn't divide into 256-lane gload calls; kept reg-staged.)
__global__ __launch_bounds__(256) void mfma_skinny(
        const unsigned short* __restrict__ A,
        const unsigned short* __restrict__ BT,
        float* __restrict__ part,
        int M, int K, int kchunk) {
    constexpr int N = 80, NT = 5;
    __shared__ unsigned short As[128][40];
    __shared__ unsigned short Bs[80][40];
    int tid = threadIdx.x;
    int row0 = blockIdx.x * 128;
    int kb = blockIdx.y * kchunk, ke = kb + kchunk;
    float* myout = part + (size_t)blockIdx.y * M * N;
    int wave = tid >> 6, lane = tid & 63;
    int wr = wave * 32;
    int lm = lane & 15, lq = lane >> 4;
    int ar0 = tid >> 2, ar1 = (tid + 256) >> 2, aseg = tid & 3;
    const unsigned short* Ap0 = A + (size_t)(row0 + ar0) * K + aseg * 8;
    const unsigned short* Ap1 = A + (size_t)(row0 + ar1) * K + aseg * 8;
    const unsigned short* Bp0 = BT + (size_t)ar0 * K + aseg * 8;   // e = tid < 320 always
    const unsigned short* Bp1 = BT + (size_t)ar1 * K + aseg * 8;   // valid only tid < 64
    bool haveB1 = (tid < 64);
    f32x4 acc[2][NT] = {};
    bf16x8 pa0 = *(const bf16x8*)(Ap0 + kb);
    bf16x8 pa1 = *(const bf16x8*)(Ap1 + kb);
    bf16x8 pb0 = *(const bf16x8*)(Bp0 + kb);
    bf16x8 pb1 = {};
    if (haveB1) pb1 = *(const bf16x8*)(Bp1 + kb);
    *(bf16x8*)&As[ar0][aseg * 8] = pa0;
    *(bf16x8*)&As[ar1][aseg * 8] = pa1;
    *(bf16x8*)&Bs[ar0][aseg * 8] = pb0;
    if (haveB1) *(bf16x8*)&Bs[ar1][aseg * 8] = pb1;
    for (int k0 = kb; k0 < ke; k0 += 32) {
        __syncthreads();
        bool more = (k0 + 32 < ke);
        if (more) {
            pa0 = *(const bf16x8*)(Ap0 + k0 + 32);
            pa1 = *(const bf16x8*)(Ap1 + k0 + 32);
            pb0 = *(const bf16x8*)(Bp0 + k0 + 32);
            if (haveB1) pb1 = *(const bf16x8*)(Bp1 + k0 + 32);
        }
        bf16x8 af[2], bfr[NT];
#pragma unroll
        for (int i = 0; i < 2; i++) af[i] = *(const bf16x8*)&As[wr + i * 16 + lm][lq * 8];
#pragma unroll
        for (int j = 0; j < NT; j++) bfr[j] = *(const bf16x8*)&Bs[j * 16 + lm][lq * 8];
#pragma unroll
        for (int i = 0; i < 2; i++)
#pragma unroll
            for (int j = 0; j < NT; j++)
                acc[i][j] = __builtin_amdgcn_mfma_f32_16x16x32_bf16(af[i], bfr[j], acc[i][j], 0, 0, 0);
        __syncthreads();
        if (more) {
            *(bf16x8*)&As[ar0][aseg * 8] = pa0;
            *(bf16x8*)&As[ar1][aseg * 8] = pa1;
            *(bf16x8*)&Bs[ar0][aseg * 8] = pb0;
            if (haveB1) *(bf16x8*)&Bs[ar1][aseg * 8] = pb1;
        }
    }
#pragma unroll
    for (int i = 0; i < 2; i++) {
#pragma unroll
        for (int ii = 0; ii < 4; ii++) {
            int row = row0 + wr + i * 16 + lq * 4 + ii;
#pragma unroll
            for (int j = 0; j < NT; j++) {
                int col = j * 16 + lm;
                myout[(size_t)row * N + col] = acc[i][j][ii];
            }
        }
    }
}

// ---------------- tiled causal conv (k=4) + silu, multi-layout out -------
__global__ __launch_bounds__(256) void conv_silu_kernel(
        const unsigned short* __restrict__ xzb,
        const float* __restrict__ cw,
        const float* __restrict__ cb,
        unsigned short* __restrict__ ub,
        float* __restrict__ uT,
        unsigned short* __restrict__ resT) {
    __shared__ unsigned short s_xz[67][66];
    __shared__ float us[64][65];
    int tid = threadIdx.x;
    int d0 = blockIdx.x * 64, r0 = blockIdx.y * 64;
    bool atStart = (r0 & (L_SEQ - 1)) == 0;
    for (int idx = tid; idx < 67 * 64; idx += 256) {
        int rr = idx >> 6, cc2 = idx & 63;
        unsigned short v = 0;
        if (rr >= 3 || !atStart)
            v = xzb[(size_t)(r0 - 3 + rr) * (2 * D_INNER) + d0 + cc2];
        s_xz[rr][cc2] = v;
    }
    __syncthreads();
    int cc = tid & 63, ty = tid >> 6;
    const float* wp = cw + (size_t)(d0 + cc) * D_CONV;
    float w0 = wp[0], w1 = wp[1], w2 = wp[2], w3 = wp[3];
    float bb = cb[d0 + cc];
    for (int rr = ty; rr < 64; rr += 4) {
        float s = bb;
        s = fmaf(bf2f(s_xz[rr + 0][cc]), w0, s);
        s = fmaf(bf2f(s_xz[rr + 1][cc]), w1, s);
        s = fmaf(bf2f(s_xz[rr + 2][cc]), w2, s);
        s = fmaf(bf2f(s_xz[rr + 3][cc]), w3, s);
        float v = silu_f(s);
        ub[(size_t)(r0 + rr) * D_INNER + d0 + cc] = f2bf(v);
        us[rr][cc] = v;
    }
    __syncthreads();
    int tx = tid & 63, dy = tid >> 6;
    for (int dd = dy; dd < 64; dd += 4)
        uT[(size_t)(d0 + dd) * ROWS + r0 + tx] = us[tx][dd];
    __syncthreads();
    for (int idx = tid; idx < 64 * 64; idx += 256) {
        int rr = idx >> 6, cc2 = idx & 63;
        s_xz[rr][cc2] = xzb[(size_t)(r0 + rr) * (2 * D_INNER) + D_INNER + d0 + cc2];
    }
    __syncthreads();
    for (int dd = dy; dd < 64; dd += 4)
        resT[(size_t)(d0 + dd) * ROWS + r0 + tx] = s_xz[tx][dd];
}

// ---------------- chunk-parallel selective scan, adaptive re-chunk -------
__global__ __launch_bounds__(256) void scan_kernel(
        const float* __restrict__ deltaT,  // (D_INNER, ROWS)
        const float* __restrict__ uT,      // (D_INNER, ROWS)
        const float* __restrict__ xdbl,    // (ROWS, 80): [.,48:64]=B, [.,64:80]=C
        const unsigned short* __restrict__ resT, // (D_INNER, ROWS) bf16
        const float* __restrict__ A_log,   // (D_INNER, 16) this layer
        const float* __restrict__ Dp,      // (D_INNER) this layer
        unsigned short* __restrict__ ygT) {// (D_INNER, ROWS) bf16 gated y
    int tid = threadIdx.x;
    int n = tid & 15, c = tid >> 4;
    int bd = blockIdx.x;
    int b = bd / D_INNER, d = bd - b * D_INNER;
    int row0 = b * L_SEQ;
    float a2 = -fast_exp(A_log[d * D_STATE + n]) * 1.44269504f;  // log2 domain
    float Dd = Dp[d];
    __shared__ float2 s_du[L_SEQ + 16];
    __shared__ float cs1[16][17];
    __shared__ float cs2[16][17];
    __shared__ float gmv[16];
    const float* dptr = deltaT + (size_t)d * ROWS + row0;
    const float* uptr = uT + (size_t)d * ROWS + row0;
    for (int e = tid; e < L_SEQ; e += 256)
        s_du[e + (e >> 6)] = make_float2(dptr[e], uptr[e]);
    __syncthreads();
    // ---- pass 1: 64-step chunk sums of dA (global l==0 excluded) ----
    {
        int l0 = c * 64, sb = l0 + c;
        bool notfirst = (c != 0);
        float sum = 0.f;
#pragma unroll 8
        for (int j = 0; j < 64; j++) {
            float dA = fmaxf(s_du[sb + j].x * a2, -28.8539008f);
            if (j > 0 || notfirst) sum += dA;
        }
        cs1[n][c] = sum;
    }
    __syncthreads();
    float cbase = 0.f;
    for (int cc = 0; cc < c; cc++) cbase += cs1[n][cc];
    float gm = cbase;
    gm = fmaxf(gm, __shfl_xor(gm, 1, 16));
    gm = fmaxf(gm, __shfl_xor(gm, 2, 16));
    gm = fmaxf(gm, __shfl_xor(gm, 4, 16));
    gm = fmaxf(gm, __shfl_xor(gm, 8, 16));
    if (n == 0) gmv[c] = gm;
    __syncthreads();
    int lc = 16;
    for (int cc = 1; cc < 16; cc++)
        if (gmv[cc] <= -150.0f) { lc = cc; break; }
    int clen = lc * 4;
    int l0b = c * clen;
    int lend = lc * 64;
    // ---- pass 1b: sub-chunk sums of dA ----
    {
        float sum = 0.f;
        for (int j = 0; j < clen; j++) {
            int l = l0b + j;
            float dA = fmaxf(s_du[l + (l >> 6)].x * a2, -28.8539008f);
            if (l > 0) sum += dA;
        }
        cs1[n][c] = sum;
    }
    __syncthreads();
    float cbase_b = 0.f;
    for (int cc = 0; cc < c; cc++) cbase_b += cs1[n][cc];
    // ---- pass 2b: sub-chunk P-term sums ----
    const float* xBbase = xdbl + (size_t)row0 * 80 + DT_RANK + n;
    {
        float Cacc = cbase_b, psum = 0.f;
        for (int j = 0; j < clen; j++) {
            int l = l0b + j;
            float2 du = s_du[l + (l >> 6)];
            float dA = fmaxf(du.x * a2, -28.8539008f);
            if (l > 0) Cacc += dA;
            float S = fast_exp2(Cacc);
            float r = fast_rcp(S + 1e-12f);
            psum = fmaf(du.x * du.y * xBbase[l * 80], r, psum);
        }
        cs2[n][c] = psum;
    }
    __syncthreads();
    float pbase = 0.f;
    for (int cc = 0; cc < c; cc++) pbase += cs2[n][cc];
    // ---- pass 3b: replay; n==0 writes raw y into s_du[.].x ----
    {
        float Cacc = cbase_b, P = pbase;
        for (int j = 0; j < clen; j++) {
            int l = l0b + j;
            float2 du = s_du[l + (l >> 6)];
            float dA = fmaxf(du.x * a2, -28.8539008f);
            if (l > 0) Cacc += dA;
            float S = fast_exp2(Cacc);
            float r = fast_rcp(S + 1e-12f);
            P = fmaf(du.x * du.y * xBbase[l * 80], r, P);
            float contrib = P * S * xBbase[l * 80 + 16];
            contrib += __shfl_xor(contrib, 1, 16);
            contrib += __shfl_xor(contrib, 2, 16);
            contrib += __shfl_xor(contrib, 4, 16);
            contrib += __shfl_xor(contrib, 8, 16);
            if (n == 0) s_du[l + (l >> 6)].x = contrib + du.y * Dd;
        }
    }
    __syncthreads();
    const unsigned short* rptr = resT + (size_t)d * ROWS + row0;
    unsigned short* yout = ygT + (size_t)d * ROWS + row0;
    for (int e = tid; e < L_SEQ; e += 256) {
        float2 v = s_du[e + (e >> 6)];
        float y = (e < lend) ? v.x : v.y * Dd;
        float res = bf2f(rptr[e]);
        yout[e] = f2bf(y * silu_f(res));
    }
}

extern "C" void kernel_launch(void* const* d_in, const int* in_sizes, int n_in,
                              void* d_out, int out_size, void* d_ws, size_t ws_size,
                              hipStream_t stream) {
    const int*   ids    = (const int*)d_in[0];
    const float* emb    = (const float*)d_in[1];
    const float* rms_w  = (const float*)d_in[2];
    const float* in_w   = (const float*)d_in[3];
    const float* conv_w = (const float*)d_in[4];
    const float* conv_b = (const float*)d_in[5];
    const float* xp_w   = (const float*)d_in[6];
    const float* dt_w   = (const float*)d_in[7];
    const float* dt_b   = (const float*)d_in[8];
    const float* A_log  = (const float*)d_in[9];
    const float* Dp     = (const float*)d_in[10];
    const float* out_w  = (const float*)d_in[11];
    const float* nf_w   = (const float*)d_in[12];
    const float* head_w = (const float*)d_in[13];
    float* out = (float*)d_out;

    // workspace layout (bytes) — total 68,329,472
    char* base = (char*)d_ws;
    float*          x      = (float*)(base + 0);                  //  6291456
    unsigned short* hb     = (unsigned short*)(base + 6291456);   //  3145728
    unsigned short* xzb    = (unsigned short*)(base + 9437184);   // 12582912 (dead after conv)
    unsigned short* ygT    = (unsigned short*)(base + 9437184);   //  6291456 (aliases xzb lo)
    unsigned short* ygb    = (unsigned short*)(base + 15728640);  //  6291456 (aliases xzb hi)
    float*          uT     = (float*)(base + 22020096);           // 12582912 [1536][2048]
    unsigned short* ub     = (unsigned short*)(base + 34603008);  //  6291456 [2048][1536]
    float*          xdbl   = (float*)(base + 40894464);           //   655360
    unsigned short* xdblb  = (unsigned short*)(base + 41549824);  //   262144
    float*          deltaT = (float*)(base + 41811968);           // 12582912 [1536][2048]
    float*          part   = (float*)(base + 41811968);           // aliases deltaT
    unsigned short* resT   = (unsigned short*)(base + 54394880);  //  6291456 [1536][2048]
    unsigned short* wt_in  = (unsigned short*)(base + 60686336);  //  4718592
    unsigned short* wt_out = (unsigned short*)(base + 65404928);  //  2359296
    unsigned short* xpT    = (unsigned short*)(base + 67764224);  //   245760
    unsigned short* dtwT   = (unsigned short*)(base + 68009984);  //   196608
    unsigned short* headT  = (unsigned short*)(base + 68206592);  //   122880

    embed_kernel<<<(ROWS * D_MODEL + 255) / 256, 256, 0, stream>>>(ids, emb, x);
    transpose_pad_bf16_kernel<<<(N_MELS * D_MODEL + 255) / 256, 256, 0, stream>>>(
        head_w, headT, D_MODEL, N_MELS, D_MODEL);

    for (int i = 0; i < N_LAYER; i++) {
        const float* in_wi   = in_w + (size_t)i * D_MODEL * 2 * D_INNER;
        const float* conv_wi = conv_w + (size_t)i * D_INNER * D_CONV;
        const float* conv_bi = conv_b + (size_t)i * D_INNER;
        const float* xp_wi   = xp_w + (size_t)i * D_INNER * (DT_RANK + 2 * D_STATE);
        const float* dt_wi   = dt_w + (size_t)i * DT_RANK * D_INNER;
        const float* dt_bi   = dt_b + (size_t)i * D_INNER;
        const float* A_li    = A_log + (size_t)i * D_INNER * D_STATE;
        const float* Dpi     = Dp + (size_t)i * D_INNER;
        const float* out_wi  = out_w + (size_t)i * D_INNER * D_MODEL;
        const float* rms_wi  = rms_w + (size_t)i * D_MODEL;

        prep_weights_kernel<<<4320, 256, 0, stream>>>(
            in_wi, out_wi, xp_wi, dt_wi, wt_in, wt_out, xpT, dtwT);

        rmsnorm_kernel<<<ROWS, 256, 0, stream>>>(x, rms_wi, hb);
        // xz = h @ in_proj_w : (2048,768)@(768,3072) -> bf16 [64x128, 768 blocks]
        mfma_gemm64<<<dim3(2 * D_INNER / 128, ROWS / 64), 256, 0, stream>>>(
            hb, wt_in, nullptr, nullptr, nullptr, xzb,
            ROWS, 2 * D_INNER, D_MODEL, 2 * D_INNER, 0, 0);
        // conv + silu -> ub (r-major), uT (d-major), resT (d-major)
        conv_silu_kernel<<<dim3(D_INNER / 64, ROWS / 64), 256, 0, stream>>>(
            xzb, conv_wi, conv_bi, ub, uT, resT);
        // x_dbl = u @ x_proj_w : split-K partials -> fused reduce+cvt
        mfma_skinny<<<dim3(ROWS / 128, 16), 256, 0, stream>>>(
            ub, xpT, part, ROWS, D_INNER, D_INNER / 16);
        reduce_cvt_kernel<<<(ROWS * 80 + 255) / 256, 256, 0, stream>>>(
            part, xdbl, xdblb, 16);
        // deltaT = softplus(dt_w^T @ x_dbl^T + dt_b): [32x128, single K-iter]
        mfma_gemm32<<<dim3(ROWS / 128, D_INNER / 32), 256, 0, stream>>>(
            dtwT, xdblb, dt_bi, nullptr, deltaT, nullptr,
            D_INNER, ROWS, 64, ROWS, 1, 1);
        // scan + gate -> ygT (d-major)
        scan_kernel<<<B_SZ * D_INNER, 256, 0, stream>>>(
            deltaT, uT, xdbl, resT, A_li, Dpi, ygT);
        // ygT -> ygb (r-major) for out_proj
        transpose_u16_kernel<<<dim3(ROWS / 32, D_INNER / 32), 256, 0, stream>>>(
            ygT, ygb, D_INNER, ROWS);
        // x = yg @ out_proj_w + x : (2048,1536)@(1536,768) [32x128, 384 blocks]
        mfma_gemm32<<<dim3(D_MODEL / 128, ROWS / 32), 256, 0, stream>>>(
            ygb, wt_out, nullptr, x, x, nullptr,
            ROWS, D_MODEL, D_INNER, D_MODEL, 0, 0);
    }

    rmsnorm_kernel<<<ROWS, 256, 0, stream>>>(x, nf_w, hb);
    // out = h @ head_w : split-K partials -> reduce (writes all of d_out)
    mfma_skinny<<<dim3(ROWS / 128, 8), 256, 0, stream>>>(
        hb, headT, part, ROWS, D_MODEL, D_MODEL / 8);
    reduce_split_kernel<<<(ROWS * N_MELS + 255) / 256, 256, 0, stream>>>(
        part, out, ROWS * N_MELS, 8);
}

// Round 4
// 681.333 us; speedup vs baseline: 1.0322x; 1.0322x over previous
//
#include <hip/hip_runtime.h>
#include <hip/hip_bf16.h>
#include <math.h>

// Model constants (fixed by the reference)
#define D_MODEL 768
#define N_LAYER 4
#define D_STATE 16
#define D_CONV  4
#define DT_RANK 48
#define D_INNER 1536
#define B_SZ    2
#define L_SEQ   1024
#define N_MELS  80
#define ROWS    (B_SZ * L_SEQ)   // 2048

typedef __bf16 bf16x8 __attribute__((ext_vector_type(8)));
typedef unsigned short u16x8 __attribute__((ext_vector_type(8)));
typedef float  f32x4  __attribute__((ext_vector_type(4)));

// raw transcendentals (1 ulp; v_exp_f32 computes 2^x)
__device__ __forceinline__ float fast_exp2(float x) {
    float r; asm("v_exp_f32 %0, %1" : "=v"(r) : "v"(x)); return r;
}
__device__ __forceinline__ float fast_exp(float x) {
    return fast_exp2(x * 1.44269504f);
}
__device__ __forceinline__ float fast_rcp(float x) {
    float r; asm("v_rcp_f32 %0, %1" : "=v"(r) : "v"(x)); return r;
}
__device__ __forceinline__ float silu_f(float v) {
    return v * fast_rcp(1.0f + fast_exp(-v));
}
__device__ __forceinline__ float softplus_f(float v) {
    return fmaxf(v, 0.0f) + log1pf(expf(-fabsf(v)));
}
__device__ __forceinline__ unsigned short f2bf(float f) {
    unsigned int u = __float_as_uint(f);
    unsigned int r = (u + 0x7FFFu + ((u >> 16) & 1u)) >> 16;
    return (unsigned short)r;
}
__device__ __forceinline__ float bf2f(unsigned short v) {
    return __uint_as_float(((unsigned int)v) << 16);
}

// ---------------- embedding gather + head-weight transpose (merged) ------
__global__ void embed_head_kernel(const int* __restrict__ ids,
                                  const float* __restrict__ emb,
                                  float* __restrict__ x,
                                  const float* __restrict__ head_w,
                                  unsigned short* __restrict__ headT) {
    int i = blockIdx.x * 256 + threadIdx.x;
    if (i < ROWS * D_MODEL) {
        int r = i / D_MODEL, c = i - r * D_MODEL;
        x[i] = emb[(size_t)ids[r] * D_MODEL + c];
    } else {
        int j = i - ROWS * D_MODEL;
        if (j < N_MELS * D_MODEL) {
            int c = j / D_MODEL, r = j - c * D_MODEL;   // headT[c][r]
            headT[j] = f2bf(head_w[(size_t)r * N_MELS + c]);
        }
    }
}

// ---------------- rmsnorm -> bf16 ----------------
__global__ void rmsnorm_kernel(const float* __restrict__ x,
                               const float* __restrict__ w,
                               unsigned short* __restrict__ hb) {
    int row = blockIdx.x;
    const float* xr = x + (size_t)row * D_MODEL;
    int tid = threadIdx.x;
    float p = 0.f;
    for (int c = tid; c < D_MODEL; c += 256) { float v = xr[c]; p = fmaf(v, v, p); }
    for (int off = 32; off >= 1; off >>= 1) p += __shfl_down(p, off, 64);
    __shared__ float ws[4];
    int lane = tid & 63, wv = tid >> 6;
    if (lane == 0) ws[wv] = p;
    __syncthreads();
    if (tid == 0) ws[0] = ws[0] + ws[1] + ws[2] + ws[3];
    __syncthreads();
    float scale = 1.0f / sqrtf(ws[0] / (float)D_MODEL + 1e-5f);
    for (int c = tid; c < D_MODEL; c += 256)
        hb[(size_t)row * D_MODEL + c] = f2bf(xr[c] * scale * w[c]);
}

// ---------------- per-layer fused weight prep (1 dispatch) ---------------
__global__ void prep_weights_kernel(const float* __restrict__ in_wi,
                                    const float* __restrict__ out_wi,
                                    const float* __restrict__ xp_wi,
                                    const float* __restrict__ dt_wi,
                                    unsigned short* __restrict__ wt_in,
                                    unsigned short* __restrict__ wt_out,
                                    unsigned short* __restrict__ xpT,
                                    unsigned short* __restrict__ dtwT) {
    __shared__ float t[32][33];
    int bx = blockIdx.x;
    int tid = threadIdx.x;
    if (bx < 3456) {
        const float* src; unsigned short* dst; int R, C, cy, cx;
        if (bx < 2304) {
            src = in_wi; dst = wt_in; R = D_MODEL; C = 2 * D_INNER;
            cy = bx / 96; cx = bx - cy * 96;
        } else {
            int tt = bx - 2304;
            src = out_wi; dst = wt_out; R = D_INNER; C = D_MODEL;
            cy = tt / 24; cx = tt - cy * 24;
        }
        int tx = tid & 31, ty = tid >> 5;
        int r0 = cy * 32, c0 = cx * 32;
#pragma unroll
        for (int i = 0; i < 4; i++)
            t[ty + i * 8][tx] = src[(size_t)(r0 + ty + i * 8) * C + c0 + tx];
        __syncthreads();
#pragma unroll
        for (int i = 0; i < 4; i++)
            dst[(size_t)(c0 + ty + i * 8) * R + r0 + tx] = f2bf(t[tx][ty + i * 8]);
    } else {
        int i = (bx - 3456) * 256 + tid;
        if (i < 80 * D_INNER) {
            int c = i / D_INNER, r = i - c * D_INNER;
            xpT[i] = f2bf(xp_wi[(size_t)r * 80 + c]);
        } else {
            int i2 = i - 80 * D_INNER;   // < 1536*64
            int c = i2 >> 6, r = i2 & 63;
            dtwT[i2] = (r < DT_RANK) ? f2bf(dt_wi[(size_t)r * D_INNER + c])
                                     : (unsigned short)0;
        }
    }
}

// ---------------- split-K reduce (+ fused bf16 [ROWS][64] cvt) -----------
__global__ void reduce_cvt_kernel(const float* __restrict__ part,
                                  float* __restrict__ xdbl,
                                  unsigned short* __restrict__ xdblb,
                                  int nsplit) {
    int i = blockIdx.x * 256 + threadIdx.x;
    if (i >= ROWS * 80) return;
    float s = 0.f;
    for (int k = 0; k < nsplit; k++) s += part[(size_t)k * ROWS * 80 + i];
    xdbl[i] = s;
    int r = i / 80, c = i - r * 80;
    if (c < DT_RANK) xdblb[r * 64 + c] = f2bf(s);
    else if (c >= 64) xdblb[r * 64 + c - 16] = 0;
}

// ---------------- plain split-K reduce (head) ----------------------------
__global__ void reduce_split_kernel(const float* __restrict__ part,
                                    float* __restrict__ dst,
                                    int MN, int nsplit) {
    int i = blockIdx.x * 256 + threadIdx.x;
    if (i >= MN) return;
    float s = 0.f;
    for (int k = 0; k < nsplit; k++) s += part[(size_t)k * MN + i];
    dst[i] = s;
}

// ---------------- bf16 MFMA GEMM, 64x128 tile, BK=64, reg-pipelined ------
// grid (N/128, M/64). R2-proven structure (682us): padded LDS (no bank
// conflicts), reg prefetch across MFMA, 2 barriers per 64-wide K-step.
__global__ __launch_bounds__(256) void mfma_gemm64(
        const unsigned short* __restrict__ A,
        const unsigned short* __restrict__ BT,
        const float* __restrict__ bias, const float* __restrict__ resid,
        float* __restrict__ Cf, unsigned short* __restrict__ Cb,
        int M, int N, int K, int ldc, int act, int bias_mode) {
    __shared__ unsigned short As[64][72];
    __shared__ unsigned short Bs[128][72];
    int tid = threadIdx.x;
    int row0 = blockIdx.y * 64, col0 = blockIdx.x * 128;
    int wave = tid >> 6, lane = tid & 63;
    int wr = (wave >> 1) * 32, wc = (wave & 1) * 64;
    int lm = lane & 15, lq = lane >> 4;
    int sr = tid >> 3, seg = tid & 7;        // 32 rows/round, 8x16B segs/row
    const unsigned short* Ap0 = A  + (size_t)(row0 + sr) * K + seg * 8;
    const unsigned short* Ap1 = A  + (size_t)(row0 + 32 + sr) * K + seg * 8;
    const unsigned short* Bp0 = BT + (size_t)(col0 + sr) * K + seg * 8;
    const unsigned short* Bp1 = BT + (size_t)(col0 + 32 + sr) * K + seg * 8;
    const unsigned short* Bp2 = BT + (size_t)(col0 + 64 + sr) * K + seg * 8;
    const unsigned short* Bp3 = BT + (size_t)(col0 + 96 + sr) * K + seg * 8;
    f32x4 acc[2][4] = {};
    bf16x8 pa0 = *(const bf16x8*)Ap0;
    bf16x8 pa1 = *(const bf16x8*)Ap1;
    bf16x8 pb0 = *(const bf16x8*)Bp0;
    bf16x8 pb1 = *(const bf16x8*)Bp1;
    bf16x8 pb2 = *(const bf16x8*)Bp2;
    bf16x8 pb3 = *(const bf16x8*)Bp3;
    *(bf16x8*)&As[sr][seg * 8]      = pa0;
    *(bf16x8*)&As[32 + sr][seg * 8] = pa1;
    *(bf16x8*)&Bs[sr][seg * 8]      = pb0;
    *(bf16x8*)&Bs[32 + sr][seg * 8] = pb1;
    *(bf16x8*)&Bs[64 + sr][seg * 8] = pb2;
    *(bf16x8*)&Bs[96 + sr][seg * 8] = pb3;
    for (int k0 = 0; k0 < K; k0 += 64) {
        __syncthreads();
        bool more = (k0 + 64 < K);
        if (more) {
            pa0 = *(const bf16x8*)(Ap0 + k0 + 64);
            pa1 = *(const bf16x8*)(Ap1 + k0 + 64);
            pb0 = *(const bf16x8*)(Bp0 + k0 + 64);
            pb1 = *(const bf16x8*)(Bp1 + k0 + 64);
            pb2 = *(const bf16x8*)(Bp2 + k0 + 64);
            pb3 = *(const bf16x8*)(Bp3 + k0 + 64);
        }
#pragma unroll
        for (int ks = 0; ks < 2; ks++) {
            bf16x8 af[2], bfr[4];
#pragma unroll
            for (int i = 0; i < 2; i++)
                af[i] = *(const bf16x8*)&As[wr + i * 16 + lm][ks * 32 + lq * 8];
#pragma unroll
            for (int j = 0; j < 4; j++)
                bfr[j] = *(const bf16x8*)&Bs[wc + j * 16 + lm][ks * 32 + lq * 8];
#pragma unroll
            for (int i = 0; i < 2; i++)
#pragma unroll
                for (int j = 0; j < 4; j++)
                    acc[i][j] = __builtin_amdgcn_mfma_f32_16x16x32_bf16(af[i], bfr[j], acc[i][j], 0, 0, 0);
        }
        __syncthreads();
        if (more) {
            *(bf16x8*)&As[sr][seg * 8]      = pa0;
            *(bf16x8*)&As[32 + sr][seg * 8] = pa1;
            *(bf16x8*)&Bs[sr][seg * 8]      = pb0;
            *(bf16x8*)&Bs[32 + sr][seg * 8] = pb1;
            *(bf16x8*)&Bs[64 + sr][seg * 8] = pb2;
            *(bf16x8*)&Bs[96 + sr][seg * 8] = pb3;
        }
    }
#pragma unroll
    for (int i = 0; i < 2; i++) {
#pragma unroll
        for (int ii = 0; ii < 4; ii++) {
            int row = row0 + wr + i * 16 + lq * 4 + ii;
#pragma unroll
            for (int j = 0; j < 4; j++) {
                int col = col0 + wc + j * 16 + lm;
                float v = acc[i][j][ii];
                if (bias) v += bias[bias_mode ? row : col];
                if (act == 1) v = softplus_f(v);
                if (resid) v += resid[(size_t)row * ldc + col];
                if (Cf) Cf[(size_t)row * ldc + col] = v;
                else    Cb[(size_t)row * ldc + col] = f2bf(v);
            }
        }
    }
}

// ---------------- bf16 MFMA GEMM, 32x128, BK=64, templated A layout ------
// AT=false: A row-major [M][K] (delta GEMM). AT=true: A is [K][M] (e.g.
// ygT from the scan) — staging does the transpose via 8x ds_write_b16 into
// the same padded As[r][k], killing the separate transpose_u16 pass (R13).
template<bool AT>
__global__ __launch_bounds__(256) void mfma_gemm32(
        const unsigned short* __restrict__ A,
        const unsigned short* __restrict__ BT,
        const float* __restrict__ bias, const float* __restrict__ resid,
        float* __restrict__ Cf, unsigned short* __restrict__ Cb,
        int M, int N, int K, int ldc, int act, int bias_mode) {
    __shared__ unsigned short As[32][72];
    __shared__ unsigned short Bs[128][72];
    int tid = threadIdx.x;
    int row0 = blockIdx.y * 32, col0 = blockIdx.x * 128;
    int wave = tid >> 6, lane = tid & 63;
    int wc = wave * 32;
    int lm = lane & 15, lq = lane >> 4;
    int sr = tid >> 3, seg = tid & 7;
    const unsigned short* Bp0 = BT + (size_t)(col0 + sr) * K + seg * 8;
    const unsigned short* Bp1 = BT + (size_t)(col0 + 32 + sr) * K + seg * 8;
    const unsigned short* Bp2 = BT + (size_t)(col0 + 64 + sr) * K + seg * 8;
    const unsigned short* Bp3 = BT + (size_t)(col0 + 96 + sr) * K + seg * 8;
    // A staging addresses
    int akk = tid >> 2, arc = (tid & 3) * 8;          // AT: kk row, r col
    const unsigned short* ApT = AT ? (A + (size_t)akk * M + row0 + arc) : nullptr;
    const unsigned short* Ap  = AT ? nullptr : (A + (size_t)(row0 + sr) * K + seg * 8);
    f32x4 acc[2][2] = {};
    u16x8 pa;
    if (AT) pa = *(const u16x8*)ApT;
    else    pa = *(const u16x8*)Ap;
    bf16x8 pb0 = *(const bf16x8*)Bp0;
    bf16x8 pb1 = *(const bf16x8*)Bp1;
    bf16x8 pb2 = *(const bf16x8*)Bp2;
    bf16x8 pb3 = *(const bf16x8*)Bp3;
    if (AT) {
#pragma unroll
        for (int j = 0; j < 8; j++) As[arc + j][akk] = pa[j];
    } else {
        *(u16x8*)&As[sr][seg * 8] = pa;
    }
    *(bf16x8*)&Bs[sr][seg * 8]      = pb0;
    *(bf16x8*)&Bs[32 + sr][seg * 8] = pb1;
    *(bf16x8*)&Bs[64 + sr][seg * 8] = pb2;
    *(bf16x8*)&Bs[96 + sr][seg * 8] = pb3;
    for (int k0 = 0; k0 < K; k0 += 64) {
        __syncthreads();
        bool more = (k0 + 64 < K);
        if (more) {
            if (AT) pa = *(const u16x8*)(ApT + (size_t)(k0 + 64) * M);
            else    pa = *(const u16x8*)(Ap + k0 + 64);
            pb0 = *(const bf16x8*)(Bp0 + k0 + 64);
            pb1 = *(const bf16x8*)(Bp1 + k0 + 64);
            pb2 = *(const bf16x8*)(Bp2 + k0 + 64);
            pb3 = *(const bf16x8*)(Bp3 + k0 + 64);
        }
#pragma unroll
        for (int ks = 0; ks < 2; ks++) {
            bf16x8 af[2], bfr[2];
#pragma unroll
            for (int i = 0; i < 2; i++)
                af[i] = *(const bf16x8*)&As[i * 16 + lm][ks * 32 + lq * 8];
#pragma unroll
            for (int j = 0; j < 2; j++)
                bfr[j] = *(const bf16x8*)&Bs[wc + j * 16 + lm][ks * 32 + lq * 8];
#pragma unroll
            for (int i = 0; i < 2; i++)
#pragma unroll
                for (int j = 0; j < 2; j++)
                    acc[i][j] = __builtin_amdgcn_mfma_f32_16x16x32_bf16(af[i], bfr[j], acc[i][j], 0, 0, 0);
        }
        __syncthreads();
        if (more) {
            if (AT) {
#pragma unroll
                for (int j = 0; j < 8; j++) As[arc + j][akk] = pa[j];
            } else {
                *(u16x8*)&As[sr][seg * 8] = pa;
            }
            *(bf16x8*)&Bs[sr][seg * 8]      = pb0;
            *(bf16x8*)&Bs[32 + sr][seg * 8] = pb1;
            *(bf16x8*)&Bs[64 + sr][seg * 8] = pb2;
            *(bf16x8*)&Bs[96 + sr][seg * 8] = pb3;
        }
    }
#pragma unroll
    for (int i = 0; i < 2; i++) {
#pragma unroll
        for (int ii = 0; ii < 4; ii++) {
            int row = row0 + i * 16 + lq * 4 + ii;
#pragma unroll
            for (int j = 0; j < 2; j++) {
                int col = col0 + wc + j * 16 + lm;
                float v = acc[i][j][ii];
                if (bias) v += bias[bias_mode ? row : col];
                if (act == 1) v = softplus_f(v);
                if (resid) v += resid[(size_t)row * ldc + col];
                if (Cf) Cf[(size_t)row * ldc + col] = v;
                else    Cb[(size_t)row * ldc + col] = f2bf(v);
            }
        }
    }
}

// ---------------- skinny split-K bf16 MFMA -> private partials -----------
// N fixed at 80 (NT=5 compile-time; R6 spill lesson). Reg-pipelined.
// AT=false: A bf16 row-major [M][K] (head). AT=true: A f32 [K][M] (uT from
// conv) — staging transposes + converts on the fly, killing the ub copy.
template<bool AT>
__global__ __launch_bounds__(256) void mfma_skinny(
        const unsigned short* __restrict__ A,
        const float* __restrict__ AfT,
        const unsigned short* __restrict__ BT,
        float* __restrict__ part,
        int M, int K, int kchunk) {
    constexpr int N = 80, NT = 5;
    __shared__ unsigned short As[128][40];
    __shared__ unsigned short Bs[80][40];
    int tid = threadIdx.x;
    int row0 = blockIdx.x * 128;
    int kb = blockIdx.y * kchunk, ke = kb + kchunk;
    float* myout = part + (size_t)blockIdx.y * M * N;
    int wave = tid >> 6, lane = tid & 63;
    int wr = wave * 32;
    int lm = lane & 15, lq = lane >> 4;
    int ar0 = tid >> 2, ar1 = (tid + 256) >> 2, aseg = tid & 3;
    const unsigned short* Ap0 = AT ? nullptr : (A + (size_t)(row0 + ar0) * K + aseg * 8);
    const unsigned short* Ap1 = AT ? nullptr : (A + (size_t)(row0 + ar1) * K + aseg * 8);
    // AT staging: 4 slots, slot l covers k-rows srl+l*8, r-cols src4..+3
    int srl = tid >> 5, src4 = (tid & 31) * 4;
    const float* Af0 = AT ? (AfT + (size_t)(srl + 0) * M + row0 + src4) : nullptr;
    const float* Af1 = AT ? (AfT + (size_t)(srl + 8) * M + row0 + src4) : nullptr;
    const float* Af2 = AT ? (AfT + (size_t)(srl + 16) * M + row0 + src4) : nullptr;
    const float* Af3 = AT ? (AfT + (size_t)(srl + 24) * M + row0 + src4) : nullptr;
    const unsigned short* Bp0 = BT + (size_t)ar0 * K + aseg * 8;   // tid < 320 always
    const unsigned short* Bp1 = BT + (size_t)ar1 * K + aseg * 8;   // valid only tid < 64
    bool haveB1 = (tid < 64);
    f32x4 acc[2][NT] = {};
    bf16x8 pa0, pa1;
    f32x4 qa0, qa1, qa2, qa3;
    if (AT) {
        qa0 = *(const f32x4*)(Af0 + (size_t)kb * M);
        qa1 = *(const f32x4*)(Af1 + (size_t)kb * M);
        qa2 = *(const f32x4*)(Af2 + (size_t)kb * M);
        qa3 = *(const f32x4*)(Af3 + (size_t)kb * M);
    } else {
        pa0 = *(const bf16x8*)(Ap0 + kb);
        pa1 = *(const bf16x8*)(Ap1 + kb);
    }
    bf16x8 pb0 = *(const bf16x8*)(Bp0 + kb);
    bf16x8 pb1 = {};
    if (haveB1) pb1 = *(const bf16x8*)(Bp1 + kb);
    if (AT) {
#pragma unroll
        for (int e = 0; e < 4; e++) {
            As[src4 + e][srl]      = f2bf(qa0[e]);
            As[src4 + e][srl + 8]  = f2bf(qa1[e]);
            As[src4 + e][srl + 16] = f2bf(qa2[e]);
            As[src4 + e][srl + 24] = f2bf(qa3[e]);
        }
    } else {
        *(bf16x8*)&As[ar0][aseg * 8] = pa0;
        *(bf16x8*)&As[ar1][aseg * 8] = pa1;
    }
    *(bf16x8*)&Bs[ar0][aseg * 8] = pb0;
    if (haveB1) *(bf16x8*)&Bs[ar1][aseg * 8] = pb1;
    for (int k0 = kb; k0 < ke; k0 += 32) {
        __syncthreads();
        bool more = (k0 + 32 < ke);
        if (more) {
            if (AT) {
                qa0 = *(const f32x4*)(Af0 + (size_t)(k0 + 32) * M);
                qa1 = *(const f32x4*)(Af1 + (size_t)(k0 + 32) * M);
                qa2 = *(const f32x4*)(Af2 + (size_t)(k0 + 32) * M);
                qa3 = *(const f32x4*)(Af3 + (size_t)(k0 + 32) * M);
            } else {
                pa0 = *(const bf16x8*)(Ap0 + k0 + 32);
                pa1 = *(const bf16x8*)(Ap1 + k0 + 32);
            }
            pb0 = *(const bf16x8*)(Bp0 + k0 + 32);
            if (haveB1) pb1 = *(const bf16x8*)(Bp1 + k0 + 32);
        }
        bf16x8 af[2], bfr[NT];
#pragma unroll
        for (int i = 0; i < 2; i++) af[i] = *(const bf16x8*)&As[wr + i * 16 + lm][lq * 8];
#pragma unroll
        for (int j = 0; j < NT; j++) bfr[j] = *(const bf16x8*)&Bs[j * 16 + lm][lq * 8];
#pragma unroll
        for (int i = 0; i < 2; i++)
#pragma unroll
            for (int j = 0; j < NT; j++)
                acc[i][j] = __builtin_amdgcn_mfma_f32_16x16x32_bf16(af[i], bfr[j], acc[i][j], 0, 0, 0);
        __syncthreads();
        if (more) {
            if (AT) {
#pragma unroll
                for (int e = 0; e < 4; e++) {
                    As[src4 + e][srl]      = f2bf(qa0[e]);
                    As[src4 + e][srl + 8]  = f2bf(qa1[e]);
                    As[src4 + e][srl + 16] = f2bf(qa2[e]);
                    As[src4 + e][srl + 24] = f2bf(qa3[e]);
                }
            } else {
                *(bf16x8*)&As[ar0][aseg * 8] = pa0;
                *(bf16x8*)&As[ar1][aseg * 8] = pa1;
            }
            *(bf16x8*)&Bs[ar0][aseg * 8] = pb0;
            if (haveB1) *(bf16x8*)&Bs[ar1][aseg * 8] = pb1;
        }
    }
#pragma unroll
    for (int i = 0; i < 2; i++) {
#pragma unroll
        for (int ii = 0; ii < 4; ii++) {
            int row = row0 + wr + i * 16 + lq * 4 + ii;
#pragma unroll
            for (int j = 0; j < NT; j++) {
                int col = j * 16 + lm;
                myout[(size_t)row * N + col] = acc[i][j][ii];
            }
        }
    }
}

// ---------------- tiled causal conv (k=4) + silu -------------------------
// outputs: uT (d-major f32), resT (d-major bf16). ub dropped (R13: skinny
// now reads uT directly with transpose-staging).
__global__ __launch_bounds__(256) void conv_silu_kernel(
        const unsigned short* __restrict__ xzb,
        const float* __restrict__ cw,
        const float* __restrict__ cb,
        float* __restrict__ uT,
        unsigned short* __restrict__ resT) {
    __shared__ unsigned short s_xz[67][66];
    __shared__ float us[64][65];
    int tid = threadIdx.x;
    int d0 = blockIdx.x * 64, r0 = blockIdx.y * 64;
    bool atStart = (r0 & (L_SEQ - 1)) == 0;
    for (int idx = tid; idx < 67 * 64; idx += 256) {
        int rr = idx >> 6, cc2 = idx & 63;
        unsigned short v = 0;
        if (rr >= 3 || !atStart)
            v = xzb[(size_t)(r0 - 3 + rr) * (2 * D_INNER) + d0 + cc2];
        s_xz[rr][cc2] = v;
    }
    __syncthreads();
    int cc = tid & 63, ty = tid >> 6;
    const float* wp = cw + (size_t)(d0 + cc) * D_CONV;
    float w0 = wp[0], w1 = wp[1], w2 = wp[2], w3 = wp[3];
    float bb = cb[d0 + cc];
    for (int rr = ty; rr < 64; rr += 4) {
        float s = bb;
        s = fmaf(bf2f(s_xz[rr + 0][cc]), w0, s);
        s = fmaf(bf2f(s_xz[rr + 1][cc]), w1, s);
        s = fmaf(bf2f(s_xz[rr + 2][cc]), w2, s);
        s = fmaf(bf2f(s_xz[rr + 3][cc]), w3, s);
        us[rr][cc] = silu_f(s);
    }
    __syncthreads();
    int tx = tid & 63, dy = tid >> 6;
    for (int dd = dy; dd < 64; dd += 4)
        uT[(size_t)(d0 + dd) * ROWS + r0 + tx] = us[tx][dd];
    __syncthreads();
    for (int idx = tid; idx < 64 * 64; idx += 256) {
        int rr = idx >> 6, cc2 = idx & 63;
        s_xz[rr][cc2] = xzb[(size_t)(r0 + rr) * (2 * D_INNER) + D_INNER + d0 + cc2];
    }
    __syncthreads();
    for (int dd = dy; dd < 64; dd += 4)
        resT[(size_t)(d0 + dd) * ROWS + r0 + tx] = s_xz[tx][dd];
}

// ---------------- chunk-parallel selective scan, adaptive re-chunk -------
__global__ __launch_bounds__(256) void scan_kernel(
        const float* __restrict__ deltaT,  // (D_INNER, ROWS)
        const float* __restrict__ uT,      // (D_INNER, ROWS)
        const float* __restrict__ xdbl,    // (ROWS, 80): [.,48:64]=B, [.,64:80]=C
        const unsigned short* __restrict__ resT, // (D_INNER, ROWS) bf16
        const float* __restrict__ A_log,   // (D_INNER, 16) this layer
        const float* __restrict__ Dp,      // (D_INNER) this layer
        unsigned short* __restrict__ ygT) {// (D_INNER, ROWS) bf16 gated y
    int tid = threadIdx.x;
    int n = tid & 15, c = tid >> 4;
    int bd = blockIdx.x;
    int b = bd / D_INNER, d = bd - b * D_INNER;
    int row0 = b * L_SEQ;
    float a2 = -fast_exp(A_log[d * D_STATE + n]) * 1.44269504f;  // log2 domain
    float Dd = Dp[d];
    __shared__ float2 s_du[L_SEQ + 16];
    __shared__ float cs1[16][17];
    __shared__ float cs2[16][17];
    __shared__ float gmv[16];
    const float* dptr = deltaT + (size_t)d * ROWS + row0;
    const float* uptr = uT + (size_t)d * ROWS + row0;
    for (int e = tid; e < L_SEQ; e += 256)
        s_du[e + (e >> 6)] = make_float2(dptr[e], uptr[e]);
    __syncthreads();
    // ---- pass 1: 64-step chunk sums of dA (global l==0 excluded) ----
    {
        int l0 = c * 64, sb = l0 + c;
        bool notfirst = (c != 0);
        float sum = 0.f;
#pragma unroll 8
        for (int j = 0; j < 64; j++) {
            float dA = fmaxf(s_du[sb + j].x * a2, -28.8539008f);
            if (j > 0 || notfirst) sum += dA;
        }
        cs1[n][c] = sum;
    }
    __syncthreads();
    float cbase = 0.f;
    for (int cc = 0; cc < c; cc++) cbase += cs1[n][cc];
    float gm = cbase;
    gm = fmaxf(gm, __shfl_xor(gm, 1, 16));
    gm = fmaxf(gm, __shfl_xor(gm, 2, 16));
    gm = fmaxf(gm, __shfl_xor(gm, 4, 16));
    gm = fmaxf(gm, __shfl_xor(gm, 8, 16));
    if (n == 0) gmv[c] = gm;
    __syncthreads();
    int lc = 16;
    for (int cc = 1; cc < 16; cc++)
        if (gmv[cc] <= -150.0f) { lc = cc; break; }
    int clen = lc * 4;
    int l0b = c * clen;
    int lend = lc * 64;
    // ---- pass 1b: sub-chunk sums of dA ----
    {
        float sum = 0.f;
        for (int j = 0; j < clen; j++) {
            int l = l0b + j;
            float dA = fmaxf(s_du[l + (l >> 6)].x * a2, -28.8539008f);
            if (l > 0) sum += dA;
        }
        cs1[n][c] = sum;
    }
    __syncthreads();
    float cbase_b = 0.f;
    for (int cc = 0; cc < c; cc++) cbase_b += cs1[n][cc];
    // ---- pass 2b: sub-chunk P-term sums ----
    const float* xBbase = xdbl + (size_t)row0 * 80 + DT_RANK + n;
    {
        float Cacc = cbase_b, psum = 0.f;
        for (int j = 0; j < clen; j++) {
            int l = l0b + j;
            float2 du = s_du[l + (l >> 6)];
            float dA = fmaxf(du.x * a2, -28.8539008f);
            if (l > 0) Cacc += dA;
            float S = fast_exp2(Cacc);
            float r = fast_rcp(S + 1e-12f);
            psum = fmaf(du.x * du.y * xBbase[l * 80], r, psum);
        }
        cs2[n][c] = psum;
    }
    __syncthreads();
    float pbase = 0.f;
    for (int cc = 0; cc < c; cc++) pbase += cs2[n][cc];
    // ---- pass 3b: replay; n==0 writes raw y into s_du[.].x ----
    {
        float Cacc = cbase_b, P = pbase;
        for (int j = 0; j < clen; j++) {
            int l = l0b + j;
            float2 du = s_du[l + (l >> 6)];
            float dA = fmaxf(du.x * a2, -28.8539008f);
            if (l > 0) Cacc += dA;
            float S = fast_exp2(Cacc);
            float r = fast_rcp(S + 1e-12f);
            P = fmaf(du.x * du.y * xBbase[l * 80], r, P);
            float contrib = P * S * xBbase[l * 80 + 16];
            contrib += __shfl_xor(contrib, 1, 16);
            contrib += __shfl_xor(contrib, 2, 16);
            contrib += __shfl_xor(contrib, 4, 16);
            contrib += __shfl_xor(contrib, 8, 16);
            if (n == 0) s_du[l + (l >> 6)].x = contrib + du.y * Dd;
        }
    }
    __syncthreads();
    const unsigned short* rptr = resT + (size_t)d * ROWS + row0;
    unsigned short* yout = ygT + (size_t)d * ROWS + row0;
    for (int e = tid; e < L_SEQ; e += 256) {
        float2 v = s_du[e + (e >> 6)];
        float y = (e < lend) ? v.x : v.y * Dd;
        float res = bf2f(rptr[e]);
        yout[e] = f2bf(y * silu_f(res));
    }
}

extern "C" void kernel_launch(void* const* d_in, const int* in_sizes, int n_in,
                              void* d_out, int out_size, void* d_ws, size_t ws_size,
                              hipStream_t stream) {
    const int*   ids    = (const int*)d_in[0];
    const float* emb    = (const float*)d_in[1];
    const float* rms_w  = (const float*)d_in[2];
    const float* in_w   = (const float*)d_in[3];
    const float* conv_w = (const float*)d_in[4];
    const float* conv_b = (const float*)d_in[5];
    const float* xp_w   = (const float*)d_in[6];
    const float* dt_w   = (const float*)d_in[7];
    const float* dt_b   = (const float*)d_in[8];
    const float* A_log  = (const float*)d_in[9];
    const float* Dp     = (const float*)d_in[10];
    const float* out_w  = (const float*)d_in[11];
    const float* nf_w   = (const float*)d_in[12];
    const float* head_w = (const float*)d_in[13];
    float* out = (float*)d_out;

    // workspace layout (bytes) — total 68,329,472
    char* base = (char*)d_ws;
    float*          x      = (float*)(base + 0);                  //  6291456
    unsigned short* hb     = (unsigned short*)(base + 6291456);   //  3145728
    unsigned short* xzb    = (unsigned short*)(base + 9437184);   // 12582912 (dead after conv)
    unsigned short* ygT    = (unsigned short*)(base + 9437184);   //  6291456 (aliases xzb lo)
    float*          uT     = (float*)(base + 22020096);           // 12582912 [1536][2048]
    float*          xdbl   = (float*)(base + 40894464);           //   655360
    unsigned short* xdblb  = (unsigned short*)(base + 41549824);  //   262144
    float*          deltaT = (float*)(base + 41811968);           // 12582912 [1536][2048]
    float*          part   = (float*)(base + 41811968);           // aliases deltaT
    unsigned short* resT   = (unsigned short*)(base + 54394880);  //  6291456 [1536][2048]
    unsigned short* wt_in  = (unsigned short*)(base + 60686336);  //  4718592
    unsigned short* wt_out = (unsigned short*)(base + 65404928);  //  2359296
    unsigned short* xpT    = (unsigned short*)(base + 67764224);  //   245760
    unsigned short* dtwT   = (unsigned short*)(base + 68009984);  //   196608
    unsigned short* headT  = (unsigned short*)(base + 68206592);  //   122880

    embed_head_kernel<<<(ROWS * D_MODEL + N_MELS * D_MODEL + 255) / 256, 256, 0, stream>>>(
        ids, emb, x, head_w, headT);

    for (int i = 0; i < N_LAYER; i++) {
        const float* in_wi   = in_w + (size_t)i * D_MODEL * 2 * D_INNER;
        const float* conv_wi = conv_w + (size_t)i * D_INNER * D_CONV;
        const float* conv_bi = conv_b + (size_t)i * D_INNER;
        const float* xp_wi   = xp_w + (size_t)i * D_INNER * (DT_RANK + 2 * D_STATE);
        const float* dt_wi   = dt_w + (size_t)i * DT_RANK * D_INNER;
        const float* dt_bi   = dt_b + (size_t)i * D_INNER;
        const float* A_li    = A_log + (size_t)i * D_INNER * D_STATE;
        const float* Dpi     = Dp + (size_t)i * D_INNER;
        const float* out_wi  = out_w + (size_t)i * D_INNER * D_MODEL;
        const float* rms_wi  = rms_w + (size_t)i * D_MODEL;

        prep_weights_kernel<<<4320, 256, 0, stream>>>(
            in_wi, out_wi, xp_wi, dt_wi, wt_in, wt_out, xpT, dtwT);

        rmsnorm_kernel<<<ROWS, 256, 0, stream>>>(x, rms_wi, hb);
        // xz = h @ in_proj_w : (2048,768)@(768,3072) -> bf16 [64x128, 768 blocks]
        mfma_gemm64<<<dim3(2 * D_INNER / 128, ROWS / 64), 256, 0, stream>>>(
            hb, wt_in, nullptr, nullptr, nullptr, xzb,
            ROWS, 2 * D_INNER, D_MODEL, 2 * D_INNER, 0, 0);
        // conv + silu -> uT (d-major f32), resT (d-major bf16)
        conv_silu_kernel<<<dim3(D_INNER / 64, ROWS / 64), 256, 0, stream>>>(
            xzb, conv_wi, conv_bi, uT, resT);
        // x_dbl = u @ x_proj_w : A staged transposed from uT (ub eliminated)
        mfma_skinny<true><<<dim3(ROWS / 128, 16), 256, 0, stream>>>(
            nullptr, uT, xpT, part, ROWS, D_INNER, D_INNER / 16);
        reduce_cvt_kernel<<<(ROWS * 80 + 255) / 256, 256, 0, stream>>>(
            part, xdbl, xdblb, 16);
        // deltaT = softplus(dt_w^T @ x_dbl^T + dt_b): [32x128, single K-iter]
        mfma_gemm32<false><<<dim3(ROWS / 128, D_INNER / 32), 256, 0, stream>>>(
            dtwT, xdblb, dt_bi, nullptr, deltaT, nullptr,
            D_INNER, ROWS, 64, ROWS, 1, 1);
        // scan + gate -> ygT (d-major)
        scan_kernel<<<B_SZ * D_INNER, 256, 0, stream>>>(
            deltaT, uT, xdbl, resT, A_li, Dpi, ygT);
        // x = yg @ out_proj_w + x : A staged transposed from ygT
        // (transpose_u16 pass eliminated)
        mfma_gemm32<true><<<dim3(D_MODEL / 128, ROWS / 32), 256, 0, stream>>>(
            ygT, wt_out, nullptr, x, x, nullptr,
            ROWS, D_MODEL, D_INNER, D_MODEL, 0, 0);
    }

    rmsnorm_kernel<<<ROWS, 256, 0, stream>>>(x, nf_w, hb);
    // out = h @ head_w : split-K partials -> reduce (writes all of d_out)
    mfma_skinny<false><<<dim3(ROWS / 128, 8), 256, 0, stream>>>(
        hb, nullptr, headT, part, ROWS, D_MODEL, D_MODEL / 8);
    reduce_split_kernel<<<(ROWS * N_MELS + 255) / 256, 256, 0, stream>>>(
        part, out, ROWS * N_MELS, 8);
}